// Round 4
// baseline (410.876 us; speedup 1.0000x reference)
//
#include <hip/hip_runtime.h>
#include <math.h>

#define NB   16
#define HH   209
#define WW   133
#define CIN  64
#define COUT 128
#define OH   201
#define OW   129
#define NTAP 19
#define NW   (NTAP*CIN*COUT)
#define NBLK (NB*OH)    // 3216 = 8 * 402: exact XCD-chunk split

#define XS 72   // bf16 elems per LDS row; 144B = 9x16B stride -> even b128 bank spread

typedef __attribute__((ext_vector_type(8))) __bf16 bf16x8;
typedef __attribute__((ext_vector_type(4))) float f32x4;
typedef __attribute__((ext_vector_type(4))) unsigned short us4;

__device__ __forceinline__ unsigned short f2bf(float f) {
  unsigned int u = __builtin_bit_cast(unsigned int, f);
  u += 0x7FFFu + ((u >> 16) & 1u);       // RNE
  return (unsigned short)(u >> 16);
}

// sparse_weights [ci][co][k] fp32  ->  wt [k][co][ci] bf16
__global__ __launch_bounds__(256) void repack_w(const float* __restrict__ w,
                                                unsigned short* __restrict__ wt) {
  int gid = blockIdx.x * 256 + threadIdx.x;   // dst index, coalesced writes
  int ci = gid & 63;
  int co = (gid >> 6) & 127;
  int k  = gid >> 13;
  wt[gid] = f2bf(w[ci * (COUT * NTAP) + co * NTAP + k]);
}

// taps grouped by dh (row): within a dh all dw share parity -> one stride-2 window/row
__global__ __launch_bounds__(256) void conv_hex_mfma(const float* __restrict__ x,
                                                     const unsigned short* __restrict__ wt,
                                                     const float* __restrict__ offs,
                                                     float* __restrict__ out) {
  constexpr int c_start[9] = {0, 1, 3, 6, 8, 11, 13, 16, 18};
  constexpr int c_cnt[9]   = {1, 2, 3, 2, 3, 2, 3, 2, 1};
  constexpr int c_k[19]  = {18, 7,17, 6, 8,16, 1, 5, 0, 9,15, 2, 4, 3,10,14, 11,13, 12};
  constexpr int c_dw[19] = { 2, 3, 1, 2, 4, 0, 3, 1, 2, 4, 0, 3, 1, 2, 4, 0, 3, 1, 2};

  __shared__ unsigned short xs[2][82 * XS];   // 2 x 11.8 KB double buffer

  const int tid  = threadIdx.x;
  const int lane = tid & 63;
  const int wv   = tid >> 6;
  const int l15  = lane & 15;
  const int quad = lane >> 4;
  const int n0   = wv * 32;

  // XCD-aware swizzle: each XCD gets a contiguous chunk of 402 logical blocks
  // (= 2 whole batches, oi-contiguous) -> x-row staging hits that XCD's L2.
  const int bid0 = blockIdx.x;
  const int lb   = (bid0 & 7) * (NBLK / 8) + (bid0 >> 3);   // bijective: 3216 = 8*402
  const int oi  = lb % OH;
  const int b   = lb / OH;
  const int par = oi & 1;
  const int na  = 65 - par;                 // same-parity columns: a in [0, na)

  int ad = oi - 100; ad = ad < 0 ? -ad : ad;
  const int lim = 128 - ad;                 // valid iff |oj-64| <= lim

  int a_lo_raw = 64 - lim - par;
  int a_lo = a_lo_raw <= 0 ? 0 : (a_lo_raw + 1) >> 1;
  int a_hi = (64 + lim - par) >> 1;
  if (a_hi > na - 1) a_hi = na - 1;

  const int f0 = a_lo >> 4;
  const int f1 = a_hi >> 4;
  const int nf = f1 - f0 + 1;               // 1..5
  const int p0 = f0 * 16;
  const int npos   = nf * 16;
  const int nchunk = (npos + 2) * 16;       // float4 chunks to stage per x-row

  float* outb = out + (size_t)(b * OH + oi) * OW * COUT;

  f32x4 acc[5][2];
  #pragma unroll
  for (int i = 0; i < 5; ++i)
    #pragma unroll
    for (int j = 0; j < 2; ++j) acc[i][j] = (f32x4){0.f, 0.f, 0.f, 0.f};

  const float* xb = x + (size_t)b * (HH * WW * CIN);

  float4 stg[6];
  bf16x8 bfrag[2][3][2][2];   // [row parity][tap][ks][cout-half]: full-row double buffer

  auto load_stg = [&](int r) {
    const float* xr = xb + (size_t)(oi + r) * (WW * CIN);
    const int rpar = (par + r) & 1;
    #pragma unroll
    for (int i = 0; i < 6; ++i) {
      int c = tid + i * 256;
      if (c < nchunk) {
        int j  = c >> 4;
        int c4 = c & 15;
        int col = rpar + 2 * (p0 + j);
        if (col > WW - 1) col = WW - 1;    // clamp; results masked in epilogue
        stg[i] = *(const float4*)(xr + (size_t)col * CIN + c4 * 4);
      }
    }
  };
  auto store_stg = [&](int buf) {
    #pragma unroll
    for (int i = 0; i < 6; ++i) {
      int c = tid + i * 256;
      if (c < nchunk) {
        int j  = c >> 4;
        int c4 = c & 15;
        us4 o;   // native casts pair into v_cvt_pk_bf16_f32 (1 inst / 2 values)
        o.x = __builtin_bit_cast(unsigned short, (__bf16)stg[i].x);
        o.y = __builtin_bit_cast(unsigned short, (__bf16)stg[i].y);
        o.z = __builtin_bit_cast(unsigned short, (__bf16)stg[i].z);
        o.w = __builtin_bit_cast(unsigned short, (__bf16)stg[i].w);
        *(us4*)(&xs[buf][j * XS + c4 * 4]) = o;
      }
    }
  };
  auto loadB = [&](int rr, int t) {         // B fragments for tap t of row rr
    const unsigned short* wb = wt + (size_t)c_k[c_start[rr] + t] * (CIN * COUT);
    #pragma unroll
    for (int j = 0; j < 2; ++j) {
      const unsigned short* wn = wb + (size_t)(n0 + j * 16 + l15) * CIN + quad * 8;
      bfrag[rr & 1][t][0][j] = *(const bf16x8*)(wn);
      bfrag[rr & 1][t][1][j] = *(const bf16x8*)(wn + 32);
    }
  };

  // prologue: B for row 0, stage x-row 0 into buf 0
  loadB(0, 0);                              // c_cnt[0] == 1
  load_stg(0);
  store_stg(0);
  __syncthreads();

  #pragma unroll
  for (int r = 0; r < 9; ++r) {
    // Issue ALL of the next interval's vmem right after the barrier:
    //  - staging loads for x-row r+1
    //  - B fragments for ALL taps of row r+1 (into the other bfrag buffer)
    // Compute below then touches no vmem; both streams get ~600cy to land, and
    // the barrier's implicit vmcnt(0) finds them already retired.
    if (r < 8) {
      load_stg(r + 1);
      #pragma unroll
      for (int t = 0; t < 3; ++t)
        if (t < c_cnt[r + 1]) loadB(r + 1, t);
    }

    // compute taps of row r from buf r&1 using bfrag[r&1] (loaded last interval)
    {
      const int st = c_start[r], cnt = c_cnt[r];
      const unsigned short* bufp = xs[r & 1];
      #pragma unroll
      for (int t = 0; t < 3; ++t) {
        if (t < cnt) {
          const int s = (par + c_dw[st + t]) >> 1;   // position shift of this tap
          #pragma unroll
          for (int ks = 0; ks < 2; ++ks) {
            #pragma unroll
            for (int mf = 0; mf < 5; ++mf) {
              if (mf < nf) {
                bf16x8 a = *(const bf16x8*)(&bufp[(mf * 16 + l15 + s) * XS + ks * 32 + quad * 8]);
                acc[mf][0] = __builtin_amdgcn_mfma_f32_16x16x32_bf16(a, bfrag[r & 1][t][ks][0], acc[mf][0], 0, 0, 0);
                acc[mf][1] = __builtin_amdgcn_mfma_f32_16x16x32_bf16(a, bfrag[r & 1][t][ks][1], acc[mf][1], 0, 0, 0);
              }
            }
          }
        }
      }
    }

    if (r < 8) {
      store_stg((r + 1) & 1);   // vm-wait for stg lands here, after ~600cy of compute
      __syncthreads();          // drains only already-settled loads
    }
  }

  // ---- zero-fill AFTER the loop: off the staging critical path; these stores
  //      overlap the epilogue VALU below ----
  {
    const float4 z = make_float4(0.f, 0.f, 0.f, 0.f);
    const int opar = par ^ 1;
    const int nopp = 65 - opar;
    for (int idx = tid; idx < nopp * 32; idx += 256) {
      int q  = idx >> 5;
      int c4 = idx & 31;
      *(float4*)(outb + (size_t)(opar + 2 * q) * COUT + c4 * 4) = z;
    }
    const int hi_start = p0 + npos;
    const int hi_cnt   = na > hi_start ? na - hi_start : 0;
    const int tot      = (p0 + hi_cnt) * 32;
    for (int idx = tid; idx < tot; idx += 256) {
      int q  = idx >> 5;
      int a  = q < p0 ? q : hi_start + (q - p0);
      int c4 = idx & 31;
      *(float4*)(outb + (size_t)(par + 2 * a) * COUT + c4 * 4) = z;
    }
  }

  // ---- epilogue: elu(conv + offset), hex-masked; C/D: col=lane&15, row=quad*4+reg ----
  const float off0 = offs[n0 + l15];
  const float off1 = offs[n0 + 16 + l15];
  #pragma unroll
  for (int mf = 0; mf < 5; ++mf) {
    if (mf < nf) {
      #pragma unroll
      for (int r = 0; r < 4; ++r) {
        int a  = (f0 + mf) * 16 + quad * 4 + r;
        int oj = par + 2 * a;
        if (oj <= OW - 1) {
          int adj = oj - 64; adj = adj < 0 ? -adj : adj;
          bool valid = adj <= lim;
          float v0 = acc[mf][0][r] + off0;
          float v1 = acc[mf][1][r] + off1;
          // elu: exp(v)-1 instead of expm1 — abs err ~1e-7, ~8x fewer VALU insts
          float e0 = v0 > 0.f ? v0 : (__expf(v0) - 1.0f);
          float e1 = v1 > 0.f ? v1 : (__expf(v1) - 1.0f);
          outb[(size_t)oj * COUT + n0 + l15]      = valid ? e0 : 0.f;
          outb[(size_t)oj * COUT + n0 + 16 + l15] = valid ? e1 : 0.f;
        }
      }
    }
  }
}

extern "C" void kernel_launch(void* const* d_in, const int* in_sizes, int n_in,
                              void* d_out, int out_size, void* d_ws, size_t ws_size,
                              hipStream_t stream) {
  const float* x   = (const float*)d_in[0];
  const float* sw  = (const float*)d_in[1];
  const float* off = (const float*)d_in[2];
  float* out = (float*)d_out;

  unsigned short* wtb = (unsigned short*)d_ws;     // 311 KB
  repack_w<<<NW / 256, 256, 0, stream>>>(sw, wtb);
  conv_hex_mfma<<<NBLK, 256, 0, stream>>>(x, wtb, off, out);
}

// Round 5
// 390.866 us; speedup vs baseline: 1.0512x; 1.0512x over previous
//
#include <hip/hip_runtime.h>
#include <math.h>

#define NB   16
#define HH   209
#define WW   133
#define CIN  64
#define COUT 128
#define OH   201
#define OW   129
#define NTAP 19
#define NW   (NTAP*CIN*COUT)
#define NBLK (NB*OH)    // 3216 = 8 * 402: exact XCD-chunk split

#define XS 72   // bf16 elems per LDS row; 144B = 9x16B stride -> even b128 bank spread

typedef __attribute__((ext_vector_type(8))) __bf16 bf16x8;
typedef __attribute__((ext_vector_type(4))) float f32x4;
typedef __attribute__((ext_vector_type(4))) unsigned short us4;

__device__ __forceinline__ unsigned short f2bf(float f) {
  unsigned int u = __builtin_bit_cast(unsigned int, f);
  u += 0x7FFFu + ((u >> 16) & 1u);       // RNE
  return (unsigned short)(u >> 16);
}

// sparse_weights [ci][co][k] fp32  ->  wt [k][co][ci] bf16
__global__ __launch_bounds__(256) void repack_w(const float* __restrict__ w,
                                                unsigned short* __restrict__ wt) {
  int gid = blockIdx.x * 256 + threadIdx.x;   // dst index, coalesced writes
  int ci = gid & 63;
  int co = (gid >> 6) & 127;
  int k  = gid >> 13;
  wt[gid] = f2bf(w[ci * (COUT * NTAP) + co * NTAP + k]);
}

// taps grouped by dh (row): within a dh all dw share parity -> one stride-2 window/row
__global__ __launch_bounds__(256) void conv_hex_mfma(const float* __restrict__ x,
                                                     const unsigned short* __restrict__ wt,
                                                     const float* __restrict__ offs,
                                                     float* __restrict__ out) {
  constexpr int c_start[9] = {0, 1, 3, 6, 8, 11, 13, 16, 18};
  constexpr int c_cnt[9]   = {1, 2, 3, 2, 3, 2, 3, 2, 1};
  constexpr int c_k[19]  = {18, 7,17, 6, 8,16, 1, 5, 0, 9,15, 2, 4, 3,10,14, 11,13, 12};
  constexpr int c_dw[19] = { 2, 3, 1, 2, 4, 0, 3, 1, 2, 4, 0, 3, 1, 2, 4, 0, 3, 1, 2};

  // 4-buffer ring: row r lives in buf r%4. Barrier only after odd rows ->
  // 5 lockstep points instead of 9, and staging runs 2 rows ahead.
  __shared__ unsigned short xs[4][82 * XS];   // 4 x 11.8 KB

  const int tid  = threadIdx.x;
  const int lane = tid & 63;
  const int wv   = tid >> 6;
  const int l15  = lane & 15;
  const int quad = lane >> 4;
  const int n0   = wv * 32;

  // XCD-aware swizzle: each XCD gets a contiguous chunk of 402 logical blocks
  // (= 2 whole batches, oi-contiguous) -> x-row staging hits that XCD's L2.
  const int bid0 = blockIdx.x;
  const int lb   = (bid0 & 7) * (NBLK / 8) + (bid0 >> 3);   // bijective: 3216 = 8*402
  const int oi  = lb % OH;
  const int b   = lb / OH;
  const int par = oi & 1;
  const int na  = 65 - par;                 // same-parity columns: a in [0, na)

  int ad = oi - 100; ad = ad < 0 ? -ad : ad;
  const int lim = 128 - ad;                 // valid iff |oj-64| <= lim

  int a_lo_raw = 64 - lim - par;
  int a_lo = a_lo_raw <= 0 ? 0 : (a_lo_raw + 1) >> 1;
  int a_hi = (64 + lim - par) >> 1;
  if (a_hi > na - 1) a_hi = na - 1;

  const int f0 = a_lo >> 4;
  const int f1 = a_hi >> 4;
  const int nf = f1 - f0 + 1;               // 1..5
  const int p0 = f0 * 16;
  const int npos   = nf * 16;
  const int nchunk = (npos + 2) * 16;       // float4 chunks to stage per x-row

  float* outb = out + (size_t)(b * OH + oi) * OW * COUT;

  f32x4 acc[5][2];
  #pragma unroll
  for (int i = 0; i < 5; ++i)
    #pragma unroll
    for (int j = 0; j < 2; ++j) acc[i][j] = (f32x4){0.f, 0.f, 0.f, 0.f};

  const float* xb = x + (size_t)b * (HH * WW * CIN);

  float4 stg[6];
  bf16x8 bfrag[3][2][2];   // single buffer; per-tap prefetch (round-3 proven)

  auto load_stg = [&](int r) {
    const float* xr = xb + (size_t)(oi + r) * (WW * CIN);
    const int rpar = (par + r) & 1;
    #pragma unroll
    for (int i = 0; i < 6; ++i) {
      int c = tid + i * 256;
      if (c < nchunk) {
        int j  = c >> 4;
        int c4 = c & 15;
        int col = rpar + 2 * (p0 + j);
        if (col > WW - 1) col = WW - 1;    // clamp; results masked in epilogue
        stg[i] = *(const float4*)(xr + (size_t)col * CIN + c4 * 4);
      }
    }
  };
  auto store_stg = [&](int buf) {
    #pragma unroll
    for (int i = 0; i < 6; ++i) {
      int c = tid + i * 256;
      if (c < nchunk) {
        int j  = c >> 4;
        int c4 = c & 15;
        us4 o;   // native casts pair into v_cvt_pk_bf16_f32 (1 inst / 2 values)
        o.x = __builtin_bit_cast(unsigned short, (__bf16)stg[i].x);
        o.y = __builtin_bit_cast(unsigned short, (__bf16)stg[i].y);
        o.z = __builtin_bit_cast(unsigned short, (__bf16)stg[i].z);
        o.w = __builtin_bit_cast(unsigned short, (__bf16)stg[i].w);
        *(us4*)(&xs[buf][j * XS + c4 * 4]) = o;
      }
    }
  };
  auto loadB = [&](int rr, int t) {         // B fragments for tap t of row rr
    const unsigned short* wb = wt + (size_t)c_k[c_start[rr] + t] * (CIN * COUT);
    #pragma unroll
    for (int j = 0; j < 2; ++j) {
      const unsigned short* wn = wb + (size_t)(n0 + j * 16 + l15) * CIN + quad * 8;
      bfrag[t][0][j] = *(const bf16x8*)(wn);
      bfrag[t][1][j] = *(const bf16x8*)(wn + 32);
    }
  };

  // prologue: B for row 0, stage x-rows 0,1 into bufs 0,1
  loadB(0, 0);                              // c_cnt[0] == 1
  load_stg(0);
  store_stg(0);
  load_stg(1);
  store_stg(1);
  __syncthreads();

  #pragma unroll
  for (int r = 0; r < 9; ++r) {
    // stage two rows ahead: loads fly under this row's compute, store lands
    // at row end when data has long arrived; the buffer (r+2)%4 == (r-2)%4 had
    // its readers (row r-2) finish before the last post-odd-row barrier.
    if (r < 7) load_stg(r + 2);

    // compute taps of row r from buf r%4; interleave B(r+1) prefetch into the
    // same bfrag slots right after tap t's last MFMA consumes them.
    {
      const int st = c_start[r], cnt = c_cnt[r];
      const unsigned short* bufp = xs[r & 3];
      #pragma unroll
      for (int t = 0; t < 3; ++t) {
        if (t < cnt) {
          const int s = (par + c_dw[st + t]) >> 1;   // position shift of this tap
          #pragma unroll
          for (int ks = 0; ks < 2; ++ks) {
            #pragma unroll
            for (int mf = 0; mf < 5; ++mf) {
              if (mf < nf) {
                bf16x8 a = *(const bf16x8*)(&bufp[(mf * 16 + l15 + s) * XS + ks * 32 + quad * 8]);
                acc[mf][0] = __builtin_amdgcn_mfma_f32_16x16x32_bf16(a, bfrag[t][ks][0], acc[mf][0], 0, 0, 0);
                acc[mf][1] = __builtin_amdgcn_mfma_f32_16x16x32_bf16(a, bfrag[t][ks][1], acc[mf][1], 0, 0, 0);
              }
            }
          }
          if (r < 8 && t < c_cnt[r + 1]) loadB(r + 1, t);   // prefetch next row's tap t
        }
      }
      if (r < 8) {                          // taps next row has but this row didn't
        #pragma unroll
        for (int t = 0; t < 3; ++t)
          if (t >= cnt && t < c_cnt[r + 1]) loadB(r + 1, t);
      }
    }

    if (r < 7) store_stg((r + 2) & 3);      // vm-wait lands after a row of compute

    if ((r & 1) == 1) __syncthreads();      // barrier after rows 1,3,5,7 only
  }

  // ---- zero-fill AFTER the loop: off the staging critical path; these stores
  //      overlap the epilogue VALU below ----
  {
    const float4 z = make_float4(0.f, 0.f, 0.f, 0.f);
    const int opar = par ^ 1;
    const int nopp = 65 - opar;
    for (int idx = tid; idx < nopp * 32; idx += 256) {
      int q  = idx >> 5;
      int c4 = idx & 31;
      *(float4*)(outb + (size_t)(opar + 2 * q) * COUT + c4 * 4) = z;
    }
    const int hi_start = p0 + npos;
    const int hi_cnt   = na > hi_start ? na - hi_start : 0;
    const int tot      = (p0 + hi_cnt) * 32;
    for (int idx = tid; idx < tot; idx += 256) {
      int q  = idx >> 5;
      int a  = q < p0 ? q : hi_start + (q - p0);
      int c4 = idx & 31;
      *(float4*)(outb + (size_t)(par + 2 * a) * COUT + c4 * 4) = z;
    }
  }

  // ---- epilogue: elu(conv + offset), hex-masked; C/D: col=lane&15, row=quad*4+reg ----
  const float off0 = offs[n0 + l15];
  const float off1 = offs[n0 + 16 + l15];
  #pragma unroll
  for (int mf = 0; mf < 5; ++mf) {
    if (mf < nf) {
      #pragma unroll
      for (int r = 0; r < 4; ++r) {
        int a  = (f0 + mf) * 16 + quad * 4 + r;
        int oj = par + 2 * a;
        if (oj <= OW - 1) {
          int adj = oj - 64; adj = adj < 0 ? -adj : adj;
          bool valid = adj <= lim;
          float v0 = acc[mf][0][r] + off0;
          float v1 = acc[mf][1][r] + off1;
          // elu: exp(v)-1 instead of expm1 — abs err ~1e-7, ~8x fewer VALU insts
          float e0 = v0 > 0.f ? v0 : (__expf(v0) - 1.0f);
          float e1 = v1 > 0.f ? v1 : (__expf(v1) - 1.0f);
          outb[(size_t)oj * COUT + n0 + l15]      = valid ? e0 : 0.f;
          outb[(size_t)oj * COUT + n0 + 16 + l15] = valid ? e1 : 0.f;
        }
      }
    }
  }
}

extern "C" void kernel_launch(void* const* d_in, const int* in_sizes, int n_in,
                              void* d_out, int out_size, void* d_ws, size_t ws_size,
                              hipStream_t stream) {
  const float* x   = (const float*)d_in[0];
  const float* sw  = (const float*)d_in[1];
  const float* off = (const float*)d_in[2];
  float* out = (float*)d_out;

  unsigned short* wtb = (unsigned short*)d_ws;     // 311 KB
  repack_w<<<NW / 256, 256, 0, stream>>>(sw, wtb);
  conv_hex_mfma<<<NBLK, 256, 0, stream>>>(x, wtb, off, out);
}